// Round 5
// baseline (1782.405 us; speedup 1.0000x reference)
//
#include <hip/hip_runtime.h>

#define NNUE_INPUTS 41024
#define L1N 128
#define L2N 32
#define L3N 32
#define NC_ROW (NNUE_INPUTS / 4)   // 10256 float4 chunks per row
#define MAXK 128                   // per (persp,row) index capacity
#define LCAP 256                   // per-wave candidate list (expected ~15, Pois tail ~0)
#define MAX_ACT 512                // fallback kernel capacity
#define NC_HALF (NC_ROW / 2)
#define WITER 20

typedef float f4 __attribute__((ext_vector_type(4)));
typedef int   i4 __attribute__((ext_vector_type(4)));

__device__ __forceinline__ float clip01(float x) {
    return fminf(fmaxf(x, 0.0f), 1.0f);
}

__device__ __forceinline__ int nzbits(const f4& x) {
    const i4 b = *(const i4*)&x;
    return (b[0] | b[1]) | (b[2] | b[3]);
}

// ---------------------------------------------------------------------------
// Kernel 0: zero the per-(persp,row) activation counters in workspace.
// ---------------------------------------------------------------------------
__global__ void zero_cnt_kernel(int* __restrict__ cnt, int n) {
    const int i = blockIdx.x * blockDim.x + threadIdx.x;
    if (i < n) cnt[i] = 0;
}

// ---------------------------------------------------------------------------
// INSTRUMENT: pure-read bandwidth probe (BabelStream-dot shaped).
// Reads w_in and b_in TWICE (2.69 GB) so it exceeds the ~415us fills and
// appears in the top-5 counter table by name, with hbm_gbps = true
// pure-read ceiling. No nt, no branches, no atomics: best-practice read.
// ---------------------------------------------------------------------------
__global__ __launch_bounds__(256, 8) void bwprobe_kernel(
    const float* __restrict__ a, const float* __restrict__ b,
    float* __restrict__ o, int nf4)
{
    const int s   = gridDim.x * blockDim.x;
    const int tid = blockIdx.x * blockDim.x + threadIdx.x;
    f4 acc = {0.f, 0.f, 0.f, 0.f};
    #pragma unroll 1
    for (int seg = 0; seg < 4; ++seg) {
        const f4* __restrict__ src = (const f4*)((seg & 1) ? b : a);
        int c = tid;
        if (c + 3 * s < nf4) {
            f4 a0 = src[c], a1 = src[c + s], a2 = src[c + 2 * s], a3 = src[c + 3 * s];
            #pragma unroll 1
            while (c + 7 * s < nf4) {
                const int cn = c + 4 * s;
                const f4 b0 = src[cn], b1 = src[cn + s];
                const f4 b2 = src[cn + 2 * s], b3 = src[cn + 3 * s];
                acc += a0; acc += a1; acc += a2; acc += a3;
                a0 = b0; a1 = b1; a2 = b2; a3 = b3;
                c = cn;
            }
            acc += a0; acc += a1; acc += a2; acc += a3;
            c += 4 * s;
        }
        for (; c < nf4; c += s) acc += src[c];
    }
    o[tid] = (acc[0] + acc[1]) + (acc[2] + acc[3]);
}

// ---------------------------------------------------------------------------
// Kernel 1 (v3): streaming scan with BALLOT-COMPACTION emit.
// The stream loop contains ZERO memory ops whose results are consumed:
// candidate offsets come from __ballot/__popcll (pure VALU), appends are
// fire-and-forget ds_writes into a per-wave LDS list, and the per-row
// global atomics happen once in a post-loop flush. Loads are pipelined
// distance-1 (8 in flight) and are never drained by emits.
// ---------------------------------------------------------------------------
__global__ __launch_bounds__(256, 8) void scan_kernel(
    const float* __restrict__ w_in, const float* __restrict__ b_in,
    int* __restrict__ cnt, int* __restrict__ idx, int nrows)
{
    __shared__ int s_list[4][LCAP];

    const int p = blockIdx.y;                  // 0 = w, 1 = b
    const f4* __restrict__ src = (const f4*)(p ? b_in : w_in);
    int* __restrict__ cntp = cnt + p * nrows;
    int* __restrict__ idxp = idx + (size_t)p * nrows * MAXK;

    const int nch  = nrows * NC_ROW;           // 42,008,576
    const int s    = gridDim.x * blockDim.x;   // 524,288
    const int lane = threadIdx.x & 63;
    const int wv   = threadIdx.x >> 6;
    const unsigned long long below = (1ull << lane) - 1ull;
    int wcount = 0;                            // wave-uniform by construction

    auto handle = [&](const f4& x, int c) {
        const i4 b = *(const i4*)&x;
        if (__any(((b[0] | b[1]) | (b[2] | b[3])) != 0)) {     // wave-uniform branch
            const unsigned long long m0 = __ballot(b[0] != 0);
            const unsigned long long m1 = __ballot(b[1] != 0);
            const unsigned long long m2 = __ballot(b[2] != 0);
            const unsigned long long m3 = __ballot(b[3] != 0);
            const int n0 = __popcll(m0), n1 = __popcll(m1), n2 = __popcll(m2);
            const int e = c << 2;              // global element id base (fits int)
            if (b[0]) s_list[wv][(wcount                + __popcll(m0 & below)) & (LCAP - 1)] = e;
            if (b[1]) s_list[wv][(wcount + n0           + __popcll(m1 & below)) & (LCAP - 1)] = e | 1;
            if (b[2]) s_list[wv][(wcount + n0 + n1      + __popcll(m2 & below)) & (LCAP - 1)] = e | 2;
            if (b[3]) s_list[wv][(wcount + n0 + n1 + n2 + __popcll(m3 & below)) & (LCAP - 1)] = e | 3;
            wcount += n0 + n1 + n2 + __popcll(m3);
        }
    };

    const int tid0 = blockIdx.x * blockDim.x + threadIdx.x;
    const int KB   = (nch / s) / 4;            // uniform full-batch count, in-bounds by construction
    int c = tid0;

    if (KB > 0) {
        f4 a0 = __builtin_nontemporal_load(src + c);
        f4 a1 = __builtin_nontemporal_load(src + c + s);
        f4 a2 = __builtin_nontemporal_load(src + c + 2 * s);
        f4 a3 = __builtin_nontemporal_load(src + c + 3 * s);
        #pragma unroll 1
        for (int k = 0; k < KB - 1; ++k) {
            const int cn = c + 4 * s;
            const f4 b0 = __builtin_nontemporal_load(src + cn);
            const f4 b1 = __builtin_nontemporal_load(src + cn + s);
            const f4 b2 = __builtin_nontemporal_load(src + cn + 2 * s);
            const f4 b3 = __builtin_nontemporal_load(src + cn + 3 * s);
            handle(a0, c);
            handle(a1, c + s);
            handle(a2, c + 2 * s);
            handle(a3, c + 3 * s);
            a0 = b0; a1 = b1; a2 = b2; a3 = b3;
            c = cn;
        }
        handle(a0, c);
        handle(a1, c + s);
        handle(a2, c + 2 * s);
        handle(a3, c + 3 * s);
        c += 4 * s;
    }
    // remainder: keep all lanes converged (__any loop), guard loads per-lane
    while (__any(c < nch)) {
        f4 x = {0.f, 0.f, 0.f, 0.f};
        if (c < nch) x = __builtin_nontemporal_load(src + c);
        handle(x, c);
        c += s;
    }

    __syncthreads();   // make per-wave ds_writes visible before flush reads

    // flush: route candidates to per-row lists (atomics OFF the stream path)
    for (int i = lane; i < wcount; i += 64) {
        const int e   = s_list[wv][i];
        const int row = e / NNUE_INPUTS;       // compiler magic-div
        const int el  = e - row * NNUE_INPUTS;
        const int q   = atomicAdd(cntp + row, 1);
        if (q < MAXK) idxp[row * MAXK + q] = el;
    }
}

// ---------------------------------------------------------------------------
// Kernel 2: per-row network eval from compacted indices. One row per block.
// ---------------------------------------------------------------------------
__global__ __launch_bounds__(256, 8) void eval_kernel(
    const float* __restrict__ us, const float* __restrict__ them,
    const float* __restrict__ W_ft, const float* __restrict__ b_ft,
    const float* __restrict__ W1, const float* __restrict__ b1,
    const float* __restrict__ W2, const float* __restrict__ b2,
    const float* __restrict__ Wo, const float* __restrict__ bo,
    const int* __restrict__ cnt, const int* __restrict__ idx,
    float* __restrict__ out, int nrows)
{
    __shared__ int   s_idx[2][MAXK];
    __shared__ float s_w[L1N];
    __shared__ float s_b[L1N];
    __shared__ float s_l0[2 * L1N];
    __shared__ float s_part[8][L2N];
    __shared__ float s_l1[L2N];
    __shared__ float s_l2[L3N];

    const int row = blockIdx.x;
    const int tid = threadIdx.x;

    const int kw = min(cnt[row], MAXK);
    const int kb = min(cnt[nrows + row], MAXK);
    const float u = us[row];
    const float t = them[row];

    {
        const int p = tid >> 7;
        const int j = tid & (MAXK - 1);
        s_idx[p][j] = idx[((size_t)p * nrows + row) * MAXK + j];
    }
    __syncthreads();

    {
        const int  ch   = tid & (L1N - 1);
        const bool is_b = tid >= L1N;
        const int* lst  = s_idx[is_b ? 1 : 0];
        const int  K    = is_b ? kb : kw;
        const float* Wc = W_ft + ch;
        float acc = b_ft[ch];
        int k = 0;
        for (; k + 4 <= K; k += 4) {
            const float f0 = Wc[(size_t)lst[k]     * L1N];
            const float f1 = Wc[(size_t)lst[k + 1] * L1N];
            const float f2 = Wc[(size_t)lst[k + 2] * L1N];
            const float f3 = Wc[(size_t)lst[k + 3] * L1N];
            acc += (f0 + f1) + (f2 + f3);
        }
        for (; k < K; ++k) acc += Wc[(size_t)lst[k] * L1N];
        if (is_b) s_b[ch] = acc; else s_w[ch] = acc;
    }
    __syncthreads();

    if (tid < L1N) {
        const float wv = s_w[tid], bv = s_b[tid];
        s_l0[tid]       = clip01(u * wv + t * bv);
        s_l0[L1N + tid] = clip01(u * bv + t * wv);
    }
    __syncthreads();

    {
        const int o  = tid & 31;
        const int ch = tid >> 5;
        float a = 0.0f;
        const int k0 = ch * 32;
        #pragma unroll
        for (int k = 0; k < 32; ++k) a += s_l0[k0 + k] * W1[(k0 + k) * L2N + o];
        s_part[ch][o] = a;
    }
    __syncthreads();
    if (tid < L2N) {
        float a = b1[tid];
        #pragma unroll
        for (int j = 0; j < 8; ++j) a += s_part[j][tid];
        s_l1[tid] = clip01(a);
    }
    __syncthreads();

    if (tid < L3N) {
        float a = b2[tid];
        #pragma unroll
        for (int k = 0; k < L2N; ++k) a += s_l1[k] * W2[k * L3N + tid];
        s_l2[tid] = clip01(a);
    }
    __syncthreads();

    if (tid == 0) {
        float a = bo[0];
        #pragma unroll
        for (int k = 0; k < L3N; ++k) a += s_l2[k] * Wo[k];
        out[row] = a;
    }
}

// ---------------------------------------------------------------------------
// Fallback: harness-verified fused kernel (R1, 1206 us), for tiny workspace.
// ---------------------------------------------------------------------------
__global__ __launch_bounds__(256, 6) void nnue_fused_kernel(
    const float* __restrict__ us, const float* __restrict__ them,
    const float* __restrict__ w_in, const float* __restrict__ b_in,
    const float* __restrict__ W_ft, const float* __restrict__ b_ft,
    const float* __restrict__ W1, const float* __restrict__ b1,
    const float* __restrict__ W2, const float* __restrict__ b2,
    const float* __restrict__ Wo, const float* __restrict__ bo,
    float* __restrict__ out)
{
    __shared__ int   s_idx_w[MAX_ACT];
    __shared__ int   s_idx_b[MAX_ACT];
    __shared__ int   s_cnt[2];
    __shared__ float s_w[L1N];
    __shared__ float s_b[L1N];
    __shared__ float s_l0[2 * L1N];
    __shared__ float s_part[8][L2N];
    __shared__ float s_l1[L2N];
    __shared__ float s_l2[L3N];

    const int row  = blockIdx.x;
    const int tid  = threadIdx.x;
    const int wave = tid >> 6;
    const int lane = tid & 63;

    if (tid < 2) s_cnt[tid] = 0;
    const float u = us[row];
    const float t = them[row];
    __syncthreads();

    {
        const int     p    = wave >> 1;
        const f4*     src  = (const f4*)((p ? b_in : w_in) + (size_t)row * NNUE_INPUTS);
        int*          mcnt = &s_cnt[p];
        int*          midx = p ? s_idx_b : s_idx_w;
        const int     base = (wave & 1) * NC_HALF;

        auto emitf4 = [&](const f4& x, int c) {
            const i4 b = *(const i4*)&x;
            const int e = c * 4;
            if (b[0]) { int q = atomicAdd(mcnt, 1); midx[q & (MAX_ACT - 1)] = e;     }
            if (b[1]) { int q = atomicAdd(mcnt, 1); midx[q & (MAX_ACT - 1)] = e + 1; }
            if (b[2]) { int q = atomicAdd(mcnt, 1); midx[q & (MAX_ACT - 1)] = e + 2; }
            if (b[3]) { int q = atomicAdd(mcnt, 1); midx[q & (MAX_ACT - 1)] = e + 3; }
        };

        int c = base + lane;
        f4 x0 = __builtin_nontemporal_load(src + c);
        f4 x1 = __builtin_nontemporal_load(src + c + 64);
        f4 x2 = __builtin_nontemporal_load(src + c + 128);
        f4 x3 = __builtin_nontemporal_load(src + c + 192);
        #pragma unroll 1
        for (int i = 0; i < WITER - 1; ++i) {
            const int cn = c + 256;
            const f4 n0 = __builtin_nontemporal_load(src + cn);
            const f4 n1 = __builtin_nontemporal_load(src + cn + 64);
            const f4 n2 = __builtin_nontemporal_load(src + cn + 128);
            const f4 n3 = __builtin_nontemporal_load(src + cn + 192);
            if (nzbits(x0)) emitf4(x0, c);
            if (nzbits(x1)) emitf4(x1, c + 64);
            if (nzbits(x2)) emitf4(x2, c + 128);
            if (nzbits(x3)) emitf4(x3, c + 192);
            x0 = n0; x1 = n1; x2 = n2; x3 = n3;
            c = cn;
        }
        if (nzbits(x0)) emitf4(x0, c);
        if (nzbits(x1)) emitf4(x1, c + 64);
        if (nzbits(x2)) emitf4(x2, c + 128);
        if (nzbits(x3)) emitf4(x3, c + 192);
        if (lane < NC_HALF - WITER * 256) {
            const int ct = base + WITER * 256 + lane;
            const f4 x = __builtin_nontemporal_load(src + ct);
            if (nzbits(x)) emitf4(x, ct);
        }
    }
    __syncthreads();

    const int kw = min(s_cnt[0], MAX_ACT);
    const int kb = min(s_cnt[1], MAX_ACT);

    {
        const int  ch   = tid & (L1N - 1);
        const bool is_b = tid >= L1N;
        const int* lst  = is_b ? s_idx_b : s_idx_w;
        const int  K    = is_b ? kb : kw;
        const float* Wc = W_ft + ch;
        float acc = b_ft[ch];
        int k = 0;
        for (; k + 4 <= K; k += 4) {
            const float f0 = Wc[(size_t)lst[k]     * L1N];
            const float f1 = Wc[(size_t)lst[k + 1] * L1N];
            const float f2 = Wc[(size_t)lst[k + 2] * L1N];
            const float f3 = Wc[(size_t)lst[k + 3] * L1N];
            acc += (f0 + f1) + (f2 + f3);
        }
        for (; k < K; ++k) acc += Wc[(size_t)lst[k] * L1N];
        if (is_b) s_b[ch] = acc; else s_w[ch] = acc;
    }
    __syncthreads();

    if (tid < L1N) {
        const float wv = s_w[tid], bv = s_b[tid];
        s_l0[tid]       = clip01(u * wv + t * bv);
        s_l0[L1N + tid] = clip01(u * bv + t * wv);
    }
    __syncthreads();

    {
        const int o  = tid & 31;
        const int ch = tid >> 5;
        float a = 0.0f;
        const int k0 = ch * 32;
        #pragma unroll
        for (int k = 0; k < 32; ++k) a += s_l0[k0 + k] * W1[(k0 + k) * L2N + o];
        s_part[ch][o] = a;
    }
    __syncthreads();
    if (tid < L2N) {
        float a = b1[tid];
        #pragma unroll
        for (int j = 0; j < 8; ++j) a += s_part[j][tid];
        s_l1[tid] = clip01(a);
    }
    __syncthreads();

    if (tid < L3N) {
        float a = b2[tid];
        #pragma unroll
        for (int k = 0; k < L2N; ++k) a += s_l1[k] * W2[k * L3N + tid];
        s_l2[tid] = clip01(a);
    }
    __syncthreads();

    if (tid == 0) {
        float a = bo[0];
        #pragma unroll
        for (int k = 0; k < L3N; ++k) a += s_l2[k] * Wo[k];
        out[row] = a;
    }
}

extern "C" void kernel_launch(void* const* d_in, const int* in_sizes, int n_in,
                              void* d_out, int out_size, void* d_ws, size_t ws_size,
                              hipStream_t stream) {
    const float* us   = (const float*)d_in[0];
    const float* them = (const float*)d_in[1];
    const float* w_in = (const float*)d_in[2];
    const float* b_in = (const float*)d_in[3];
    const float* W_ft = (const float*)d_in[4];
    const float* b_ft = (const float*)d_in[5];
    const float* W1   = (const float*)d_in[6];
    const float* b1   = (const float*)d_in[7];
    const float* W2   = (const float*)d_in[8];
    const float* b2   = (const float*)d_in[9];
    const float* Wo   = (const float*)d_in[10];
    const float* bo   = (const float*)d_in[11];
    float* out = (float*)d_out;

    const int B = in_sizes[0];  // 4096

    // ws layout: cnt[2B] | idx[2B*MAXK] | probe_out[524288 floats]
    const size_t sz_cnt   = (size_t)2 * B * sizeof(int);
    const size_t sz_idx   = (size_t)2 * B * MAXK * sizeof(int);
    const size_t sz_probe = (size_t)524288 * sizeof(float);
    const size_t need_split = sz_cnt + sz_idx;
    const size_t need_full  = need_split + sz_probe;

    if (d_ws != nullptr && ws_size >= need_split) {
        int* cnt = (int*)d_ws;
        int* idx = cnt + 2 * B;
        zero_cnt_kernel<<<dim3((2 * B + 255) / 256), dim3(256), 0, stream>>>(cnt, 2 * B);
        scan_kernel<<<dim3(2048, 2), dim3(256), 0, stream>>>(w_in, b_in, cnt, idx, B);
        eval_kernel<<<dim3(B), dim3(256), 0, stream>>>(
            us, them, W_ft, b_ft, W1, b1, W2, b2, Wo, bo, cnt, idx, out, B);
        if (ws_size >= need_full) {
            float* probe_out = (float*)((char*)d_ws + need_split);
            bwprobe_kernel<<<dim3(2048), dim3(256), 0, stream>>>(
                w_in, b_in, probe_out, B * NC_ROW);
        }
    } else {
        nnue_fused_kernel<<<dim3(B), dim3(256), 0, stream>>>(
            us, them, w_in, b_in, W_ft, b_ft, W1, b1, W2, b2, Wo, bo, out);
    }
}

// Round 6
// 1301.026 us; speedup vs baseline: 1.3700x; 1.3700x over previous
//
#include <hip/hip_runtime.h>

#define NNUE_INPUTS 41024
#define L1N 128
#define L2N 32
#define L3N 32
#define NC_ROW (NNUE_INPUTS / 4)   // 10256 float4 chunks per row
#define MAXK 128                   // per (persp,row) index capacity
#define LCAP 256                   // per-wave candidate list (expected ~15, Pois tail ~0)
#define MAX_ACT 512                // fallback kernel capacity
#define NC_HALF (NC_ROW / 2)
#define WITER 20

typedef float f4 __attribute__((ext_vector_type(4)));
typedef int   i4 __attribute__((ext_vector_type(4)));

__device__ __forceinline__ float clip01(float x) {
    return fminf(fmaxf(x, 0.0f), 1.0f);
}

__device__ __forceinline__ int nzbits(const f4& x) {
    const i4 b = *(const i4*)&x;
    return (b[0] | b[1]) | (b[2] | b[3]);
}

// ---------------------------------------------------------------------------
// Kernel 0: zero the per-(persp,row) activation counters in workspace.
// ---------------------------------------------------------------------------
__global__ void zero_cnt_kernel(int* __restrict__ cnt, int n) {
    const int i = blockIdx.x * blockDim.x + threadIdx.x;
    if (i < n) cnt[i] = 0;
}

// ---------------------------------------------------------------------------
// Kernel 1 (v3b): ballot-compaction scan, PLAIN (cached) loads.
// Single variable vs R5: __builtin_nontemporal_load -> plain load. The R5
// bwprobe sustained 4.75 TB/s logical with plain loads while every nt scan
// sat at ~3.5-3.8; nt serves no purpose in the split design (scan and eval
// do not overlap, W_ft residency doesn't matter during the scan).
// ---------------------------------------------------------------------------
__global__ __launch_bounds__(256, 8) void scan_kernel(
    const float* __restrict__ w_in, const float* __restrict__ b_in,
    int* __restrict__ cnt, int* __restrict__ idx, int nrows)
{
    __shared__ int s_list[4][LCAP];

    const int p = blockIdx.y;                  // 0 = w, 1 = b
    const f4* __restrict__ src = (const f4*)(p ? b_in : w_in);
    int* __restrict__ cntp = cnt + p * nrows;
    int* __restrict__ idxp = idx + (size_t)p * nrows * MAXK;

    const int nch  = nrows * NC_ROW;           // 42,008,576
    const int s    = gridDim.x * blockDim.x;   // 524,288
    const int lane = threadIdx.x & 63;
    const int wv   = threadIdx.x >> 6;
    const unsigned long long below = (1ull << lane) - 1ull;
    int wcount = 0;                            // wave-uniform by construction

    auto handle = [&](const f4& x, int c) {
        const i4 b = *(const i4*)&x;
        if (__any(((b[0] | b[1]) | (b[2] | b[3])) != 0)) {     // wave-uniform branch
            const unsigned long long m0 = __ballot(b[0] != 0);
            const unsigned long long m1 = __ballot(b[1] != 0);
            const unsigned long long m2 = __ballot(b[2] != 0);
            const unsigned long long m3 = __ballot(b[3] != 0);
            const int n0 = __popcll(m0), n1 = __popcll(m1), n2 = __popcll(m2);
            const int e = c << 2;              // global element id base (fits int)
            if (b[0]) s_list[wv][(wcount                + __popcll(m0 & below)) & (LCAP - 1)] = e;
            if (b[1]) s_list[wv][(wcount + n0           + __popcll(m1 & below)) & (LCAP - 1)] = e | 1;
            if (b[2]) s_list[wv][(wcount + n0 + n1      + __popcll(m2 & below)) & (LCAP - 1)] = e | 2;
            if (b[3]) s_list[wv][(wcount + n0 + n1 + n2 + __popcll(m3 & below)) & (LCAP - 1)] = e | 3;
            wcount += n0 + n1 + n2 + __popcll(m3);
        }
    };

    const int tid0 = blockIdx.x * blockDim.x + threadIdx.x;
    const int KB   = (nch / s) / 4;            // uniform full-batch count
    int c = tid0;

    if (KB > 0) {
        f4 a0 = src[c];
        f4 a1 = src[c + s];
        f4 a2 = src[c + 2 * s];
        f4 a3 = src[c + 3 * s];
        #pragma unroll 1
        for (int k = 0; k < KB - 1; ++k) {
            const int cn = c + 4 * s;
            const f4 b0 = src[cn];
            const f4 b1 = src[cn + s];
            const f4 b2 = src[cn + 2 * s];
            const f4 b3 = src[cn + 3 * s];
            handle(a0, c);
            handle(a1, c + s);
            handle(a2, c + 2 * s);
            handle(a3, c + 3 * s);
            a0 = b0; a1 = b1; a2 = b2; a3 = b3;
            c = cn;
        }
        handle(a0, c);
        handle(a1, c + s);
        handle(a2, c + 2 * s);
        handle(a3, c + 3 * s);
        c += 4 * s;
    }
    // remainder: keep all lanes converged (__any loop), guard loads per-lane
    while (__any(c < nch)) {
        f4 x = {0.f, 0.f, 0.f, 0.f};
        if (c < nch) x = src[c];
        handle(x, c);
        c += s;
    }

    __syncthreads();   // make per-wave ds_writes visible before flush reads

    // flush: route candidates to per-row lists (atomics OFF the stream path)
    for (int i = lane; i < wcount; i += 64) {
        const int e   = s_list[wv][i];
        const int row = e / NNUE_INPUTS;       // compiler magic-div
        const int el  = e - row * NNUE_INPUTS;
        const int q   = atomicAdd(cntp + row, 1);
        if (q < MAXK) idxp[row * MAXK + q] = el;
    }
}

// ---------------------------------------------------------------------------
// Kernel 2: per-row network eval from compacted indices. One row per block.
// ---------------------------------------------------------------------------
__global__ __launch_bounds__(256, 8) void eval_kernel(
    const float* __restrict__ us, const float* __restrict__ them,
    const float* __restrict__ W_ft, const float* __restrict__ b_ft,
    const float* __restrict__ W1, const float* __restrict__ b1,
    const float* __restrict__ W2, const float* __restrict__ b2,
    const float* __restrict__ Wo, const float* __restrict__ bo,
    const int* __restrict__ cnt, const int* __restrict__ idx,
    float* __restrict__ out, int nrows)
{
    __shared__ int   s_idx[2][MAXK];
    __shared__ float s_w[L1N];
    __shared__ float s_b[L1N];
    __shared__ float s_l0[2 * L1N];
    __shared__ float s_part[8][L2N];
    __shared__ float s_l1[L2N];
    __shared__ float s_l2[L3N];

    const int row = blockIdx.x;
    const int tid = threadIdx.x;

    const int kw = min(cnt[row], MAXK);
    const int kb = min(cnt[nrows + row], MAXK);
    const float u = us[row];
    const float t = them[row];

    {
        const int p = tid >> 7;
        const int j = tid & (MAXK - 1);
        s_idx[p][j] = idx[((size_t)p * nrows + row) * MAXK + j];
    }
    __syncthreads();

    {
        const int  ch   = tid & (L1N - 1);
        const bool is_b = tid >= L1N;
        const int* lst  = s_idx[is_b ? 1 : 0];
        const int  K    = is_b ? kb : kw;
        const float* Wc = W_ft + ch;
        float acc = b_ft[ch];
        int k = 0;
        for (; k + 4 <= K; k += 4) {
            const float f0 = Wc[(size_t)lst[k]     * L1N];
            const float f1 = Wc[(size_t)lst[k + 1] * L1N];
            const float f2 = Wc[(size_t)lst[k + 2] * L1N];
            const float f3 = Wc[(size_t)lst[k + 3] * L1N];
            acc += (f0 + f1) + (f2 + f3);
        }
        for (; k < K; ++k) acc += Wc[(size_t)lst[k] * L1N];
        if (is_b) s_b[ch] = acc; else s_w[ch] = acc;
    }
    __syncthreads();

    if (tid < L1N) {
        const float wv = s_w[tid], bv = s_b[tid];
        s_l0[tid]       = clip01(u * wv + t * bv);
        s_l0[L1N + tid] = clip01(u * bv + t * wv);
    }
    __syncthreads();

    {
        const int o  = tid & 31;
        const int ch = tid >> 5;
        float a = 0.0f;
        const int k0 = ch * 32;
        #pragma unroll
        for (int k = 0; k < 32; ++k) a += s_l0[k0 + k] * W1[(k0 + k) * L2N + o];
        s_part[ch][o] = a;
    }
    __syncthreads();
    if (tid < L2N) {
        float a = b1[tid];
        #pragma unroll
        for (int j = 0; j < 8; ++j) a += s_part[j][tid];
        s_l1[tid] = clip01(a);
    }
    __syncthreads();

    if (tid < L3N) {
        float a = b2[tid];
        #pragma unroll
        for (int k = 0; k < L2N; ++k) a += s_l1[k] * W2[k * L3N + tid];
        s_l2[tid] = clip01(a);
    }
    __syncthreads();

    if (tid == 0) {
        float a = bo[0];
        #pragma unroll
        for (int k = 0; k < L3N; ++k) a += s_l2[k] * Wo[k];
        out[row] = a;
    }
}

// ---------------------------------------------------------------------------
// Fallback: harness-verified fused kernel (R1, 1206 us), for tiny workspace.
// ---------------------------------------------------------------------------
__global__ __launch_bounds__(256, 6) void nnue_fused_kernel(
    const float* __restrict__ us, const float* __restrict__ them,
    const float* __restrict__ w_in, const float* __restrict__ b_in,
    const float* __restrict__ W_ft, const float* __restrict__ b_ft,
    const float* __restrict__ W1, const float* __restrict__ b1,
    const float* __restrict__ W2, const float* __restrict__ b2,
    const float* __restrict__ Wo, const float* __restrict__ bo,
    float* __restrict__ out)
{
    __shared__ int   s_idx_w[MAX_ACT];
    __shared__ int   s_idx_b[MAX_ACT];
    __shared__ int   s_cnt[2];
    __shared__ float s_w[L1N];
    __shared__ float s_b[L1N];
    __shared__ float s_l0[2 * L1N];
    __shared__ float s_part[8][L2N];
    __shared__ float s_l1[L2N];
    __shared__ float s_l2[L3N];

    const int row  = blockIdx.x;
    const int tid  = threadIdx.x;
    const int wave = tid >> 6;
    const int lane = tid & 63;

    if (tid < 2) s_cnt[tid] = 0;
    const float u = us[row];
    const float t = them[row];
    __syncthreads();

    {
        const int     p    = wave >> 1;
        const f4*     src  = (const f4*)((p ? b_in : w_in) + (size_t)row * NNUE_INPUTS);
        int*          mcnt = &s_cnt[p];
        int*          midx = p ? s_idx_b : s_idx_w;
        const int     base = (wave & 1) * NC_HALF;

        auto emitf4 = [&](const f4& x, int c) {
            const i4 b = *(const i4*)&x;
            const int e = c * 4;
            if (b[0]) { int q = atomicAdd(mcnt, 1); midx[q & (MAX_ACT - 1)] = e;     }
            if (b[1]) { int q = atomicAdd(mcnt, 1); midx[q & (MAX_ACT - 1)] = e + 1; }
            if (b[2]) { int q = atomicAdd(mcnt, 1); midx[q & (MAX_ACT - 1)] = e + 2; }
            if (b[3]) { int q = atomicAdd(mcnt, 1); midx[q & (MAX_ACT - 1)] = e + 3; }
        };

        int c = base + lane;
        f4 x0 = src[c];
        f4 x1 = src[c + 64];
        f4 x2 = src[c + 128];
        f4 x3 = src[c + 192];
        #pragma unroll 1
        for (int i = 0; i < WITER - 1; ++i) {
            const int cn = c + 256;
            const f4 n0 = src[cn];
            const f4 n1 = src[cn + 64];
            const f4 n2 = src[cn + 128];
            const f4 n3 = src[cn + 192];
            if (nzbits(x0)) emitf4(x0, c);
            if (nzbits(x1)) emitf4(x1, c + 64);
            if (nzbits(x2)) emitf4(x2, c + 128);
            if (nzbits(x3)) emitf4(x3, c + 192);
            x0 = n0; x1 = n1; x2 = n2; x3 = n3;
            c = cn;
        }
        if (nzbits(x0)) emitf4(x0, c);
        if (nzbits(x1)) emitf4(x1, c + 64);
        if (nzbits(x2)) emitf4(x2, c + 128);
        if (nzbits(x3)) emitf4(x3, c + 192);
        if (lane < NC_HALF - WITER * 256) {
            const int ct = base + WITER * 256 + lane;
            const f4 x = src[ct];
            if (nzbits(x)) emitf4(x, ct);
        }
    }
    __syncthreads();

    const int kw = min(s_cnt[0], MAX_ACT);
    const int kb = min(s_cnt[1], MAX_ACT);

    {
        const int  ch   = tid & (L1N - 1);
        const bool is_b = tid >= L1N;
        const int* lst  = is_b ? s_idx_b : s_idx_w;
        const int  K    = is_b ? kb : kw;
        const float* Wc = W_ft + ch;
        float acc = b_ft[ch];
        int k = 0;
        for (; k + 4 <= K; k += 4) {
            const float f0 = Wc[(size_t)lst[k]     * L1N];
            const float f1 = Wc[(size_t)lst[k + 1] * L1N];
            const float f2 = Wc[(size_t)lst[k + 2] * L1N];
            const float f3 = Wc[(size_t)lst[k + 3] * L1N];
            acc += (f0 + f1) + (f2 + f3);
        }
        for (; k < K; ++k) acc += Wc[(size_t)lst[k] * L1N];
        if (is_b) s_b[ch] = acc; else s_w[ch] = acc;
    }
    __syncthreads();

    if (tid < L1N) {
        const float wv = s_w[tid], bv = s_b[tid];
        s_l0[tid]       = clip01(u * wv + t * bv);
        s_l0[L1N + tid] = clip01(u * bv + t * wv);
    }
    __syncthreads();

    {
        const int o  = tid & 31;
        const int ch = tid >> 5;
        float a = 0.0f;
        const int k0 = ch * 32;
        #pragma unroll
        for (int k = 0; k < 32; ++k) a += s_l0[k0 + k] * W1[(k0 + k) * L2N + o];
        s_part[ch][o] = a;
    }
    __syncthreads();
    if (tid < L2N) {
        float a = b1[tid];
        #pragma unroll
        for (int j = 0; j < 8; ++j) a += s_part[j][tid];
        s_l1[tid] = clip01(a);
    }
    __syncthreads();

    if (tid < L3N) {
        float a = b2[tid];
        #pragma unroll
        for (int k = 0; k < L2N; ++k) a += s_l1[k] * W2[k * L3N + tid];
        s_l2[tid] = clip01(a);
    }
    __syncthreads();

    if (tid == 0) {
        float a = bo[0];
        #pragma unroll
        for (int k = 0; k < L3N; ++k) a += s_l2[k] * Wo[k];
        out[row] = a;
    }
}

extern "C" void kernel_launch(void* const* d_in, const int* in_sizes, int n_in,
                              void* d_out, int out_size, void* d_ws, size_t ws_size,
                              hipStream_t stream) {
    const float* us   = (const float*)d_in[0];
    const float* them = (const float*)d_in[1];
    const float* w_in = (const float*)d_in[2];
    const float* b_in = (const float*)d_in[3];
    const float* W_ft = (const float*)d_in[4];
    const float* b_ft = (const float*)d_in[5];
    const float* W1   = (const float*)d_in[6];
    const float* b1   = (const float*)d_in[7];
    const float* W2   = (const float*)d_in[8];
    const float* b2   = (const float*)d_in[9];
    const float* Wo   = (const float*)d_in[10];
    const float* bo   = (const float*)d_in[11];
    float* out = (float*)d_out;

    const int B = in_sizes[0];  // 4096

    // ws layout: cnt[2B] | idx[2B*MAXK]  (~4.2 MB)
    const size_t need = ((size_t)2 * B + (size_t)2 * B * MAXK) * sizeof(int);
    if (d_ws != nullptr && ws_size >= need) {
        int* cnt = (int*)d_ws;
        int* idx = cnt + 2 * B;
        zero_cnt_kernel<<<dim3((2 * B + 255) / 256), dim3(256), 0, stream>>>(cnt, 2 * B);
        scan_kernel<<<dim3(2048, 2), dim3(256), 0, stream>>>(w_in, b_in, cnt, idx, B);
        eval_kernel<<<dim3(B), dim3(256), 0, stream>>>(
            us, them, W_ft, b_ft, W1, b1, W2, b2, Wo, bo, cnt, idx, out, B);
    } else {
        nnue_fused_kernel<<<dim3(B), dim3(256), 0, stream>>>(
            us, them, w_in, b_in, W_ft, b_ft, W1, b1, W2, b2, Wo, bo, out);
    }
}

// Round 7
// 1206.335 us; speedup vs baseline: 1.4775x; 1.0785x over previous
//
#include <hip/hip_runtime.h>

#define NNUE_INPUTS 41024
#define L1N 128
#define L2N 32
#define L3N 32
#define MAX_ACT 256                // per-perspective row list capacity (lambda~30)
#define WCAP 128                   // per-wave half-row candidate list (lambda~15)
#define NC_ROW (NNUE_INPUTS / 4)   // 10256 float4 chunks per row
#define NC_HALF (NC_ROW / 2)       // 5128 chunks per half-row (per wave)
#define WITER 20                   // 20*256 = 5120 chunks; tail = 8 per wave

typedef float f4 __attribute__((ext_vector_type(4)));
typedef int   i4 __attribute__((ext_vector_type(4)));

__device__ __forceinline__ float clip01(float x) {
    return fminf(fmaxf(x, 0.0f), 1.0f);
}

// ---------------------------------------------------------------------------
// Fused NNUE kernel, one row per block, 4 waves.
//   Phase 1: each wave streams one contiguous half-row of w_in/b_in with
//     NONTEMPORAL loads (R6 A/B: plain loads cost 0.8 TB/s via L2 thrash),
//     distance-1 pipelined (8 dwordx4 in flight). Nonzero detect = integer OR
//     (values are exactly 0.0/1.0). Emit = BALLOT-COMPACTION (R5): offsets
//     from __ballot/__popcll prefix (pure VALU), appends are fire-and-forget
//     ds_writes into a per-wave list -- zero lgkm round trips in the stream
//     loop. Per-wave lists are flushed to the per-perspective row list once.
//   Phase 2-5: W_ft gather + perspective mix + 3-layer MLP (verified since R0).
// ---------------------------------------------------------------------------
__global__ __launch_bounds__(256, 6) void nnue_fused_kernel(
    const float* __restrict__ us, const float* __restrict__ them,
    const float* __restrict__ w_in, const float* __restrict__ b_in,
    const float* __restrict__ W_ft, const float* __restrict__ b_ft,
    const float* __restrict__ W1, const float* __restrict__ b1,
    const float* __restrict__ W2, const float* __restrict__ b2,
    const float* __restrict__ Wo, const float* __restrict__ bo,
    float* __restrict__ out)
{
    __shared__ int   s_wl[4][WCAP];      // per-wave candidate lists
    __shared__ int   s_idx[2][MAX_ACT];  // per-perspective row lists
    __shared__ int   s_cnt[2];
    __shared__ float s_w[L1N];
    __shared__ float s_b[L1N];
    __shared__ float s_l0[2 * L1N];
    __shared__ float s_part[8][L2N];
    __shared__ float s_l1[L2N];
    __shared__ float s_l2[L3N];

    const int row  = blockIdx.x;
    const int tid  = threadIdx.x;
    const int wave = tid >> 6;          // 0..3
    const int lane = tid & 63;

    if (tid < 2) s_cnt[tid] = 0;
    const float u = us[row];
    const float t = them[row];
    __syncthreads();

    // ---- Phase 1: dense contiguous stream per wave, ballot-compaction emit
    {
        const int p    = wave >> 1;                     // 0 = w, 1 = b
        const f4* src  = (const f4*)((p ? b_in : w_in) + (size_t)row * NNUE_INPUTS);
        const int base = (wave & 1) * NC_HALF;          // chunk offset of this wave's half
        const unsigned long long below = (1ull << lane) - 1ull;
        int wcount = 0;                                 // wave-uniform by construction

        auto handle = [&](const f4& x, int c) {
            const i4 b = *(const i4*)&x;
            if (__any(((b[0] | b[1]) | (b[2] | b[3])) != 0)) {   // wave-uniform branch
                const unsigned long long m0 = __ballot(b[0] != 0);
                const unsigned long long m1 = __ballot(b[1] != 0);
                const unsigned long long m2 = __ballot(b[2] != 0);
                const unsigned long long m3 = __ballot(b[3] != 0);
                const int n0 = __popcll(m0), n1 = __popcll(m1), n2 = __popcll(m2);
                const int e = c << 2;                   // element index base in row
                if (b[0]) s_wl[wave][(wcount                + __popcll(m0 & below)) & (WCAP - 1)] = e;
                if (b[1]) s_wl[wave][(wcount + n0           + __popcll(m1 & below)) & (WCAP - 1)] = e | 1;
                if (b[2]) s_wl[wave][(wcount + n0 + n1      + __popcll(m2 & below)) & (WCAP - 1)] = e | 2;
                if (b[3]) s_wl[wave][(wcount + n0 + n1 + n2 + __popcll(m3 & below)) & (WCAP - 1)] = e | 3;
                wcount += n0 + n1 + n2 + __popcll(m3);
            }
        };

        // distance-1 pipelined: wave-iter i covers chunks [base+i*256, base+(i+1)*256)
        int c = base + lane;
        f4 x0 = __builtin_nontemporal_load(src + c);
        f4 x1 = __builtin_nontemporal_load(src + c + 64);
        f4 x2 = __builtin_nontemporal_load(src + c + 128);
        f4 x3 = __builtin_nontemporal_load(src + c + 192);
        #pragma unroll 1
        for (int i = 0; i < WITER - 1; ++i) {
            const int cn = c + 256;
            const f4 n0 = __builtin_nontemporal_load(src + cn);
            const f4 n1 = __builtin_nontemporal_load(src + cn + 64);
            const f4 n2 = __builtin_nontemporal_load(src + cn + 128);
            const f4 n3 = __builtin_nontemporal_load(src + cn + 192);
            handle(x0, c);
            handle(x1, c + 64);
            handle(x2, c + 128);
            handle(x3, c + 192);
            x0 = n0; x1 = n1; x2 = n2; x3 = n3;
            c = cn;
        }
        handle(x0, c);
        handle(x1, c + 64);
        handle(x2, c + 128);
        handle(x3, c + 192);

        // tail: last 8 chunks of this wave's half on lanes 0..7; all lanes
        // stay converged (x = 0 for lanes >= 8 -> no ballot bits, no emit)
        {
            const int ct = base + WITER * 256 + lane;
            f4 x = {0.f, 0.f, 0.f, 0.f};
            if (lane < NC_HALF - WITER * 256) x = __builtin_nontemporal_load(src + ct);
            handle(x, ct);
        }

        // flush this wave's list into the per-perspective row list
        int flbase = 0;
        if (lane == 0) flbase = atomicAdd(&s_cnt[p], wcount);
        flbase = __shfl(flbase, 0);
        for (int i = lane; i < wcount; i += 64) {
            const int q = flbase + i;
            if (q < MAX_ACT) s_idx[p][q] = s_wl[wave][i];
        }
    }
    __syncthreads();

    const int kw = min(s_cnt[0], MAX_ACT);
    const int kb = min(s_cnt[1], MAX_ACT);

    // ---- Phase 2: gather W_ft rows (thread = (persp, channel)) ----
    {
        const int  ch   = tid & (L1N - 1);
        const bool is_b = tid >= L1N;
        const int* lst  = s_idx[is_b ? 1 : 0];
        const int  K    = is_b ? kb : kw;
        const float* Wc = W_ft + ch;
        float acc = b_ft[ch];
        int k = 0;
        for (; k + 4 <= K; k += 4) {
            const float f0 = Wc[(size_t)lst[k]     * L1N];
            const float f1 = Wc[(size_t)lst[k + 1] * L1N];
            const float f2 = Wc[(size_t)lst[k + 2] * L1N];
            const float f3 = Wc[(size_t)lst[k + 3] * L1N];
            acc += (f0 + f1) + (f2 + f3);
        }
        for (; k < K; ++k) acc += Wc[(size_t)lst[k] * L1N];
        if (is_b) s_b[ch] = acc; else s_w[ch] = acc;
    }
    __syncthreads();

    // ---- Phase 3: perspective mix + clip -> l0 [256] ----
    if (tid < L1N) {
        const float wv = s_w[tid], bv = s_b[tid];
        s_l0[tid]       = clip01(u * wv + t * bv);
        s_l0[L1N + tid] = clip01(u * bv + t * wv);
    }
    __syncthreads();

    // ---- l1 = clip(l0 @ W1 + b1): 8 chunks x 32 outputs ----
    {
        const int o  = tid & 31;
        const int ch = tid >> 5;
        float a = 0.0f;
        const int k0 = ch * 32;
        #pragma unroll
        for (int k = 0; k < 32; ++k) a += s_l0[k0 + k] * W1[(k0 + k) * L2N + o];
        s_part[ch][o] = a;
    }
    __syncthreads();
    if (tid < L2N) {
        float a = b1[tid];
        #pragma unroll
        for (int j = 0; j < 8; ++j) a += s_part[j][tid];
        s_l1[tid] = clip01(a);
    }
    __syncthreads();

    // ---- l2 = clip(l1 @ W2 + b2) ----
    if (tid < L3N) {
        float a = b2[tid];
        #pragma unroll
        for (int k = 0; k < L2N; ++k) a += s_l1[k] * W2[k * L3N + tid];
        s_l2[tid] = clip01(a);
    }
    __syncthreads();

    // ---- out = l2 @ Wo + bo ----
    if (tid == 0) {
        float a = bo[0];
        #pragma unroll
        for (int k = 0; k < L3N; ++k) a += s_l2[k] * Wo[k];
        out[row] = a;
    }
}

extern "C" void kernel_launch(void* const* d_in, const int* in_sizes, int n_in,
                              void* d_out, int out_size, void* d_ws, size_t ws_size,
                              hipStream_t stream) {
    const float* us   = (const float*)d_in[0];
    const float* them = (const float*)d_in[1];
    const float* w_in = (const float*)d_in[2];
    const float* b_in = (const float*)d_in[3];
    const float* W_ft = (const float*)d_in[4];
    const float* b_ft = (const float*)d_in[5];
    const float* W1   = (const float*)d_in[6];
    const float* b1   = (const float*)d_in[7];
    const float* W2   = (const float*)d_in[8];
    const float* b2   = (const float*)d_in[9];
    const float* Wo   = (const float*)d_in[10];
    const float* bo   = (const float*)d_in[11];
    float* out = (float*)d_out;

    const int B = in_sizes[0];  // 4096
    nnue_fused_kernel<<<dim3(B), dim3(256), 0, stream>>>(
        us, them, w_in, b_in, W_ft, b_ft, W1, b1, W2, b2, Wo, bo, out);
}